// Round 13
// baseline (437.984 us; speedup 1.0000x reference)
//
#include <hip/hip_runtime.h>
#include <hip/hip_bf16.h>

#define E_ 8
#define H_ 2048
#define I_ 5632
#define B_ 1024
#define K_ 2
#define NROWS (B_*K_)

#define BM 128
#define MAXT 24           // sum_e ceil(cnt_e/128) <= 16 + 8

// gateup: BN=128, BK=32 (512-B weight slivers)
#define GBN 128
#define GBK 32
#define NK2 (H_/GBK)      // 64
#define NYG2 (I_/GBN)     // 44

// down: BN=64, BK=64 (R8-proven)
#define BN 64
#define BK 64
#define NKD (I_/BK)       // 88
#define NYD (H_/BN)       // 32

typedef __attribute__((ext_vector_type(8))) __bf16 bf16x8;
typedef __attribute__((ext_vector_type(4))) float f32x4;

union BF4 { __bf16 b[4]; uint2 q; };
union BF8 { __bf16 b[8]; uint4 q; };

__device__ __forceinline__ void gld_lds16(const void* g, void* l) {
  __builtin_amdgcn_global_load_lds(
      (const __attribute__((address_space(1))) void*)g,
      (__attribute__((address_space(3))) void*)l, 16, 0, 0);
}

#define GLOAD4(dst, ptr) asm volatile("global_load_dwordx4 %0, %1, off" : "=v"(dst) : "v"(ptr))
#define WAITV(N) do { asm volatile("s_waitcnt vmcnt(" #N ")" ::: "memory"); __builtin_amdgcn_sched_barrier(0); } while(0)
#define WAITL()  do { asm volatile("s_waitcnt lgkmcnt(0)" ::: "memory"); __builtin_amdgcn_sched_barrier(0); } while(0)
#define BAR()    __builtin_amdgcn_s_barrier()

#define MSK(c) (((c)&7) ^ (((c)>>2)&7))   // down-kernel swizzle (R8-verified)

// ---------------- phase 0: x (f32) -> xb (bf16) ----------------
__global__ void cvtx_kernel(const float* __restrict__ x, __bf16* __restrict__ xb) {
  int i = (blockIdx.x * 256 + threadIdx.x) * 8;
  float4 a = *(const float4*)(x + i);
  float4 b = *(const float4*)(x + i + 4);
  BF8 r;
  r.b[0] = (__bf16)a.x; r.b[1] = (__bf16)a.y; r.b[2] = (__bf16)a.z; r.b[3] = (__bf16)a.w;
  r.b[4] = (__bf16)b.x; r.b[5] = (__bf16)b.y; r.b[6] = (__bf16)b.z; r.b[7] = (__bf16)b.w;
  *(uint4*)(xb + i) = r.q;
}

// ---------------- phase 1: routing + dense tile list ----------------
__global__ void route_kernel(const int* __restrict__ ids,
                             int* __restrict__ counts, int* __restrict__ offsets,
                             int* __restrict__ tlist, int* __restrict__ row_of,
                             int* __restrict__ tile_e, int* __restrict__ tile_m) {
  __shared__ int sc[E_], sp[E_], so[E_];
  int t = threadIdx.x;
  if (t < E_) { sc[t] = 0; sp[t] = 0; }
  __syncthreads();
  for (int idx = t; idx < NROWS; idx += 256) atomicAdd(&sc[ids[idx]], 1);
  __syncthreads();
  if (t == 0) {
    int acc = 0;
    for (int e = 0; e < E_; ++e) { so[e] = acc; acc += sc[e]; }
    int nt = 0;
    for (int e = 0; e < E_; ++e)
      for (int m0 = 0; m0 < sc[e]; m0 += BM) { tile_e[nt] = e; tile_m[nt] = m0; ++nt; }
    for (; nt < MAXT; ++nt) { tile_e[nt] = 0; tile_m[nt] = 0x7FFFFFFF; }
  }
  __syncthreads();
  for (int idx = t; idx < NROWS; idx += 256) {
    int e = ids[idx];
    int slot = atomicAdd(&sp[e], 1);
    int row = so[e] + slot;
    tlist[row] = idx / K_;
    row_of[idx] = row;
  }
  if (t < E_) { counts[t] = sc[t]; offsets[t] = so[t]; }
}

// ---------------- phase 2: gate+up dual GEMM + SiLU (bf16 act) ----------------
// 128x128 tile, BK=32. Weight k-rows fetched as 512-B contiguous slivers.
// k-slot-major LDS: A[ks][r^(ks<<2)], B[ks][(q^(i<<2))+32i]. A dbuf 16K +
// B dbuf 32K = 48 KB. One barrier/phase; counted vmcnt, steady 9 outstanding.
// PF reg set is consumed (CVW) BEFORE reissue — no WAR race (R12 fix).
__global__ __launch_bounds__(256, 2) void gateup_kernel(
    const __bf16* __restrict__ xb, const float* __restrict__ gw,
    const float* __restrict__ uw, const int* __restrict__ counts,
    const int* __restrict__ offsets, const int* __restrict__ tlist,
    const int* __restrict__ tile_e, const int* __restrict__ tile_m,
    __bf16* __restrict__ act)
{
  extern __shared__ char smem[];
  char* As0 = smem;                 // 8192: 4 ks x 128 slots x 16 B
  char* As1 = smem + 8192;
  char* Bg0 = smem + 16384;         // 8192 each, k-slot-major
  char* Bu0 = smem + 24576;
  char* Bg1 = smem + 32768;
  char* Bu1 = smem + 40960;

  const int id = blockIdx.x;                  // [0, 1056)
  const int w  = (id & 7) * 132 + (id >> 3);  // XCD chunking (1056 = 8*132)
  const int tt = w % MAXT;                    // panel sharers adjacent
  const int ny = w / MAXT;                    // [0, 44)
  const int e  = tile_e[tt];
  const int m0 = tile_m[tt];
  const int cnt = counts[e];
  if (m0 >= cnt) return;
  const int off = offsets[e];
  const int n0 = ny * GBN;

  const int tid  = threadIdx.x;
  const int lane = tid & 63;
  const int wave = tid >> 6;         // 0..3
  const int wr = (wave >> 1) * 64;   // rows 0,64
  const int wc = (wave & 1) * 64;    // cols 0,64

  // ---- A glda sources: 2 granules/thread; LDS linear; source row pre-unswizzled
  const __bf16* asrc0; const __bf16* asrc1;
  int ad0, ad1;
  {
    const __bf16* s[2]; int d[2];
#pragma unroll
    for (int j = 0; j < 2; ++j) {
      int g = j*256 + tid;           // granule 0..511
      int ks = g >> 7;               // 0..3
      int sl = g & 127;
      int r  = sl ^ (ks << 2);       // inverse of slot = r ^ (ks<<2)
      int rr = m0 + r; if (rr >= cnt) rr = cnt - 1;
      int tok = tlist[off + rr];
      s[j] = xb + (size_t)tok * H_ + ks*8;
      d[j] = g * 16;
    }
    asrc0=s[0]; asrc1=s[1]; ad0=d[0]; ad1=d[1];
  }

  // ---- B staging: thread owns cols 4q..4q+3, k-rows kb..kb+3 (dwordx4 PF)
  const int q  = tid & 31;
  const int kb = (tid >> 5) * 4;     // 0..28
  const float* pg0 = gw + ((size_t)e*H_ + kb + 0)*I_ + n0 + 4*q;
  const float* pg1 = gw + ((size_t)e*H_ + kb + 1)*I_ + n0 + 4*q;
  const float* pg2 = gw + ((size_t)e*H_ + kb + 2)*I_ + n0 + 4*q;
  const float* pg3 = gw + ((size_t)e*H_ + kb + 3)*I_ + n0 + 4*q;
  const float* pu0 = uw + ((size_t)e*H_ + kb + 0)*I_ + n0 + 4*q;
  const float* pu1 = uw + ((size_t)e*H_ + kb + 1)*I_ + n0 + 4*q;
  const float* pu2 = uw + ((size_t)e*H_ + kb + 2)*I_ + n0 + 4*q;
  const float* pu3 = uw + ((size_t)e*H_ + kb + 3)*I_ + n0 + 4*q;
  int bw0, bw1, bw2, bw3;
  {
    int ksw  = kb >> 3;              // k-slot
    int half = (kb & 4) << 1;        // 0 or 8 bytes
    int b[4];
#pragma unroll
    for (int i = 0; i < 4; ++i) {
      int slot = (q ^ (i << 2)) + (i << 5);
      b[i] = ksw*2048 + slot*16 + half;
    }
    bw0=b[0]; bw1=b[1]; bw2=b[2]; bw3=b[3];
  }

  // ---- COMPUTE read offsets
  const int ks = lane >> 4;                    // 0..3
  int aofs0;                                   // A: + mi*256
  int bofs0, bofs1, bofs2, bofs3;              // B: per ni
  {
    int r0 = wr + (lane & 15);
    aofs0 = ks*2048 + ((r0 ^ (ks << 2)) << 4);
    int c0 = wc + (lane & 15);
    int ii = c0 & 3;
    int bb[4];
#pragma unroll
    for (int ni = 0; ni < 4; ++ni) {
      int qq = (c0 >> 2) + ni*4;
      int slot = (qq ^ (ii << 2)) + (ii << 5);
      bb[ni] = ks*2048 + slot*16;
    }
    bofs0=bb[0]; bofs1=bb[1]; bofs2=bb[2]; bofs3=bb[3];
  }

  f32x4 vg_0,vg_1,vg_2,vg_3, vu_0,vu_1,vu_2,vu_3;   // single PF set

  f32x4 accg[4][4], accu[4][4];
#pragma unroll
  for (int i = 0; i < 4; ++i)
#pragma unroll
    for (int j = 0; j < 4; ++j) {
      accg[i][j] = (f32x4){0.f,0.f,0.f,0.f};
      accu[i][j] = (f32x4){0.f,0.f,0.f,0.f};
    }

  auto COMPUTE = [&](const char* Ap, const char* Bgp, const char* Bup) {
    __builtin_amdgcn_s_setprio(1);
    bf16x8 a0 = *(const bf16x8*)(Ap + aofs0 + 0*256);
    bf16x8 a1 = *(const bf16x8*)(Ap + aofs0 + 1*256);
    bf16x8 a2 = *(const bf16x8*)(Ap + aofs0 + 2*256);
    bf16x8 a3 = *(const bf16x8*)(Ap + aofs0 + 3*256);
#define MM(ACC, A, B) ACC = __builtin_amdgcn_mfma_f32_16x16x32_bf16(A, B, ACC, 0,0,0)
    { // g-half
      bf16x8 b0 = *(const bf16x8*)(Bgp + bofs0);
      bf16x8 b1 = *(const bf16x8*)(Bgp + bofs1);
      bf16x8 b2 = *(const bf16x8*)(Bgp + bofs2);
      bf16x8 b3 = *(const bf16x8*)(Bgp + bofs3);
      MM(accg[0][0], a0, b0); MM(accg[1][0], a1, b0); MM(accg[2][0], a2, b0); MM(accg[3][0], a3, b0);
      MM(accg[0][1], a0, b1); MM(accg[1][1], a1, b1); MM(accg[2][1], a2, b1); MM(accg[3][1], a3, b1);
      MM(accg[0][2], a0, b2); MM(accg[1][2], a1, b2); MM(accg[2][2], a2, b2); MM(accg[3][2], a3, b2);
      MM(accg[0][3], a0, b3); MM(accg[1][3], a1, b3); MM(accg[2][3], a2, b3); MM(accg[3][3], a3, b3);
    }
    { // u-half (B-frag regs reused)
      bf16x8 b0 = *(const bf16x8*)(Bup + bofs0);
      bf16x8 b1 = *(const bf16x8*)(Bup + bofs1);
      bf16x8 b2 = *(const bf16x8*)(Bup + bofs2);
      bf16x8 b3 = *(const bf16x8*)(Bup + bofs3);
      MM(accu[0][0], a0, b0); MM(accu[1][0], a1, b0); MM(accu[2][0], a2, b0); MM(accu[3][0], a3, b0);
      MM(accu[0][1], a0, b1); MM(accu[1][1], a1, b1); MM(accu[2][1], a2, b1); MM(accu[3][1], a3, b1);
      MM(accu[0][2], a0, b2); MM(accu[1][2], a1, b2); MM(accu[2][2], a2, b2); MM(accu[3][2], a3, b2);
      MM(accu[0][3], a0, b3); MM(accu[1][3], a1, b3); MM(accu[2][3], a2, b3); MM(accu[3][3], a3, b3);
    }
#undef MM
    __builtin_amdgcn_s_setprio(0);
  };

#define GU_PF(KPF) do { size_t o_ = (size_t)(KPF)*(size_t)GBK*(size_t)I_; \
    GLOAD4(vg_0, pg0+o_); GLOAD4(vu_0, pu0+o_); \
    GLOAD4(vg_1, pg1+o_); GLOAD4(vu_1, pu1+o_); \
    GLOAD4(vg_2, pg2+o_); GLOAD4(vu_2, pu2+o_); \
    GLOAD4(vg_3, pg3+o_); GLOAD4(vu_3, pu3+o_); } while(0)

#define GU_CVW1(BB, V0, V1, V2, V3, BWI, I) do { BF4 p_; \
    p_.b[0]=(__bf16)V0[I]; p_.b[1]=(__bf16)V1[I]; p_.b[2]=(__bf16)V2[I]; p_.b[3]=(__bf16)V3[I]; \
    *(uint2*)((BB)+BWI) = p_.q; } while(0)

#define GU_CVW(BG, BU) do { \
    GU_CVW1(BG, vg_0, vg_1, vg_2, vg_3, bw0, 0); \
    GU_CVW1(BG, vg_0, vg_1, vg_2, vg_3, bw1, 1); \
    GU_CVW1(BG, vg_0, vg_1, vg_2, vg_3, bw2, 2); \
    GU_CVW1(BG, vg_0, vg_1, vg_2, vg_3, bw3, 3); \
    GU_CVW1(BU, vu_0, vu_1, vu_2, vu_3, bw0, 0); \
    GU_CVW1(BU, vu_0, vu_1, vu_2, vu_3, bw1, 1); \
    GU_CVW1(BU, vu_0, vu_1, vu_2, vu_3, bw2, 2); \
    GU_CVW1(BU, vu_0, vu_1, vu_2, vu_3, bw3, 3); } while(0)

#define GU_GLDA(DST, KPF) do { size_t k_ = (size_t)(KPF)*(size_t)GBK; \
    gld_lds16(asrc0 + k_, (DST)+ad0); gld_lds16(asrc1 + k_, (DST)+ad1); } while(0)

  // ---- prologue: loop-top invariant = PF(kt+1):8 + glda(kt+1):1 = 9
  GU_PF(0);             // 8
  WAITV(0);             // PF(0) regs ready
  GU_CVW(Bg0, Bu0);     // B(0) -> buf0
  GU_GLDA(As0, 0);      // 1
  GU_PF(1);             // -> 9
  WAITV(8);             // retire glda(0): As0 landed (own wave)
  GU_GLDA(As1, 1);      // -> 9
  WAITL();              // ds_writes committed
  BAR();                // As0 + B(0) visible

#pragma unroll 1
  for (int kt = 0; kt < NK2; kt += 2) {
    { // even: compute As0/B0; CVW kt+1 -> buf1; PF kt+2; glda As0 <- kt+2
      int kpf = kt + 2; if (kpf > NK2-1) kpf = NK2-1;
      COMPUTE(As0, Bg0, Bu0);
      WAITV(1);                    // retire PF(kt+1); keep glda(kt+1)
      GU_CVW(Bg1, Bu1);            // buf1 not in use -> no barrier needed
      GU_PF(kpf);                  // regs consumed; -> 9
      WAITV(8);                    // retire glda(kt+1): As1 landed (own wave)
      WAITL();                     // CVW writes committed
      BAR();                       // As1+B1 visible; As0 free (all computed)
      GU_GLDA(As0, kpf);           // -> 9
    }
    { // odd: mirror
      int kpf = kt + 3; if (kpf > NK2-1) kpf = NK2-1;
      COMPUTE(As1, Bg1, Bu1);
      WAITV(1);
      GU_CVW(Bg0, Bu0);
      GU_PF(kpf);
      WAITV(8);
      WAITL();
      BAR();
      GU_GLDA(As1, kpf);
    }
  }
  WAITV(0);
  WAITL();

  // ---- epilogue: SiLU(g)*u -> bf16 act
  const int rsub = (lane >> 4) * 4;
  const int csub = lane & 15;
#pragma unroll
  for (int mi = 0; mi < 4; ++mi)
#pragma unroll
    for (int j = 0; j < 4; ++j) {
      int rl = wr + mi*16 + rsub + j;
      if (m0 + rl < cnt) {
        size_t orow = (size_t)(off + m0 + rl) * I_ + n0 + wc + csub;
#pragma unroll
        for (int ni = 0; ni < 4; ++ni) {
          float g = accg[mi][ni][j];
          float u = accu[mi][ni][j];
          float sg = g / (1.0f + __expf(-g));
          act[orow + ni*16] = (__bf16)(sg * u);
        }
      }
    }
#undef GU_PF
#undef GU_CVW
#undef GU_CVW1
#undef GU_GLDA
}

// ---------------- phase 3: down GEMM -> rowbuf (f32) ----------------
// R8-proven: 48 KB LDS -> 3 blocks/CU. Steady outstanding 8 (PF:4 + GLDA:4).
__global__ __launch_bounds__(256, 3) void down_kernel(
    const __bf16* __restrict__ act, const float* __restrict__ dw,
    const int* __restrict__ counts, const int* __restrict__ offsets,
    const int* __restrict__ tile_e, const int* __restrict__ tile_m,
    float* __restrict__ rowbuf)
{
  extern __shared__ char smem[];
  char* As0 = smem;
  char* As1 = smem + 16384;
  char* Bs0 = smem + 32768;
  char* Bs1 = smem + 40960;

  const int id = blockIdx.x;                  // [0, 768)
  const int w  = (id & 7) * 96 + (id >> 3);   // 768 = 8*96
  const int tt = w % MAXT;
  const int ny = w / MAXT;                    // [0, 32)
  const int e  = tile_e[tt];
  const int m0 = tile_m[tt];
  const int cnt = counts[e];
  if (m0 >= cnt) return;
  const int off = offsets[e];
  const int n0 = ny * BN;

  const int tid  = threadIdx.x;
  const int lane = tid & 63;
  const int wave = tid >> 6;
  const int wr = (wave >> 1) * 64;
  const int wc = (wave & 1) * 32;

  const __bf16* asrc0; const __bf16* asrc1; const __bf16* asrc2; const __bf16* asrc3;
  int ad0, ad1, ad2, ad3;
  {
    const __bf16* s[4]; int d[4];
#pragma unroll
    for (int i = 0; i < 4; ++i) {
      int f = i*256 + tid;
      int r = f >> 3, cs = f & 7;
      int rr = m0 + r; if (rr >= cnt) rr = cnt - 1;
      s[i] = act + (size_t)(off + rr) * I_ + ((cs ^ (r & 7)) << 3);
      d[i] = f * 16;
    }
    asrc0=s[0]; asrc1=s[1]; asrc2=s[2]; asrc3=s[3];
    ad0=d[0]; ad1=d[1]; ad2=d[2]; ad3=d[3];
  }

  const int cq = tid & 15;
  const int kb = (tid >> 4) * 4;
  const float* pd0 = dw + ((size_t)e*I_ + kb + 0)*H_ + n0 + 4*cq;
  const float* pd1 = dw + ((size_t)e*I_ + kb + 1)*H_ + n0 + 4*cq;
  const float* pd2 = dw + ((size_t)e*I_ + kb + 2)*H_ + n0 + 4*cq;
  const float* pd3 = dw + ((size_t)e*I_ + kb + 3)*H_ + n0 + 4*cq;
  const int slot = kb >> 3;
  const int half = (kb & 4) << 1;
  int bw0, bw1, bw2, bw3;
  {
    int b[4];
#pragma unroll
    for (int i = 0; i < 4; ++i) {
      int c = 4*cq + i;
      b[i] = c*128 + ((slot ^ MSK(c)) << 4) + half;
    }
    bw0=b[0]; bw1=b[1]; bw2=b[2]; bw3=b[3];
  }

  f32x4 vdA_0,vdA_1,vdA_2,vdA_3;
  f32x4 vdB_0,vdB_1,vdB_2,vdB_3;

  f32x4 acc[4][2];
#pragma unroll
  for (int i = 0; i < 4; ++i)
#pragma unroll
    for (int j = 0; j < 2; ++j) acc[i][j] = (f32x4){0.f,0.f,0.f,0.f};

  auto COMPUTE = [&](const char* Ab, const char* Bb) {
    __builtin_amdgcn_s_setprio(1);
#pragma unroll
    for (int kk = 0; kk < 2; ++kk) {
      const int ks = kk*4 + (lane >> 4);
      const int r0 = wr + (lane & 15);
      const int swa = (ks ^ (r0 & 7)) << 4;
      bf16x8 a0 = *(const bf16x8*)(Ab + (r0 +  0)*128 + swa);
      bf16x8 a1 = *(const bf16x8*)(Ab + (r0 + 16)*128 + swa);
      bf16x8 a2 = *(const bf16x8*)(Ab + (r0 + 32)*128 + swa);
      bf16x8 a3 = *(const bf16x8*)(Ab + (r0 + 48)*128 + swa);
      const int c0 = wc + (lane & 15);
      const int swb0 = (ks ^ MSK(c0)) << 4;
      const int swb1 = swb0 ^ (4 << 4);
      bf16x8 b0 = *(const bf16x8*)(Bb + c0*128 + swb0);
      bf16x8 b1 = *(const bf16x8*)(Bb + (c0+16)*128 + swb1);
      acc[0][0] = __builtin_amdgcn_mfma_f32_16x16x32_bf16(a0, b0, acc[0][0], 0,0,0);
      acc[1][0] = __builtin_amdgcn_mfma_f32_16x16x32_bf16(a1, b0, acc[1][0], 0,0,0);
      acc[2][0] = __builtin_amdgcn_mfma_f32_16x16x32_bf16(a2, b0, acc[2][0], 0,0,0);
      acc[3][0] = __builtin_amdgcn_mfma_f32_16x16x32_bf16(a3, b0, acc[3][0], 0,0,0);
      acc[0][1] = __builtin_amdgcn_mfma_f32_16x16x32_bf16(a0, b1, acc[0][1], 0,0,0);
      acc[1][1] = __builtin_amdgcn_mfma_f32_16x16x32_bf16(a1, b1, acc[1][1], 0,0,0);
      acc[2][1] = __builtin_amdgcn_mfma_f32_16x16x32_bf16(a2, b1, acc[2][1], 0,0,0);
      acc[3][1] = __builtin_amdgcn_mfma_f32_16x16x32_bf16(a3, b1, acc[3][1], 0,0,0);
    }
    __builtin_amdgcn_s_setprio(0);
  };

#define DN_PF(S, KPF) do { size_t o_ = (size_t)(KPF)*(size_t)BK*(size_t)H_; \
    GLOAD4(vd##S##_0, pd0+o_); GLOAD4(vd##S##_1, pd1+o_); \
    GLOAD4(vd##S##_2, pd2+o_); GLOAD4(vd##S##_3, pd3+o_); } while(0)

#define DN_CVW1(BB, V0, V1, V2, V3, BWI, I) do { BF4 p_; \
    p_.b[0]=(__bf16)V0[I]; p_.b[1]=(__bf16)V1[I]; p_.b[2]=(__bf16)V2[I]; p_.b[3]=(__bf16)V3[I]; \
    *(uint2*)((BB)+BWI) = p_.q; } while(0)

#define DN_CVW(S, BB) do { \
    DN_CVW1(BB, vd##S##_0, vd##S##_1, vd##S##_2, vd##S##_3, bw0, 0); \
    DN_CVW1(BB, vd##S##_0, vd##S##_1, vd##S##_2, vd##S##_3, bw1, 1); \
    DN_CVW1(BB, vd##S##_0, vd##S##_1, vd##S##_2, vd##S##_3, bw2, 2); \
    DN_CVW1(BB, vd##S##_0, vd##S##_1, vd##S##_2, vd##S##_3, bw3, 3); } while(0)

#define DN_GLDA(DST, KPF) do { size_t k_ = (size_t)(KPF)*(size_t)BK; \
    gld_lds16(asrc0 + k_, (DST)+ad0); gld_lds16(asrc1 + k_, (DST)+ad1); \
    gld_lds16(asrc2 + k_, (DST)+ad2); gld_lds16(asrc3 + k_, (DST)+ad3); } while(0)

  DN_PF(A, 0);          // 4
  DN_GLDA(As0, 0);      // -> 8
  WAITV(4);             // drain PF(0)
  DN_CVW(A, Bs0);
  DN_PF(B, 1);          // -> 8
  DN_GLDA(As1, 1);      // -> 12
  WAITV(8);             // drain GLDA(0); PF(1)+GLDA(1)=8 left
  WAITL();
  BAR();

#pragma unroll 1
  for (int kt = 0; kt < NKD; kt += 2) {
    {
      int kpf = kt + 2; if (kpf > NKD-1) kpf = NKD-1;
      DN_PF(A, kpf);               // -> 12
      COMPUTE(As0, Bs0);
      WAITV(8);                    // drain PF_B(kt+1)
      DN_CVW(B, Bs1);
      WAITV(4);                    // drain GLDA(kt+1)
      WAITL();
      BAR();
      DN_GLDA(As0, kpf);           // -> 8
    }
    {
      int kpf = kt + 3; if (kpf > NKD-1) kpf = NKD-1;
      DN_PF(B, kpf);
      COMPUTE(As1, Bs1);
      WAITV(8);
      DN_CVW(A, Bs0);
      WAITV(4);
      WAITL();
      BAR();
      DN_GLDA(As1, kpf);
    }
  }
  WAITV(0);
  WAITL();

  const int rsub = (lane >> 4) * 4;
  const int csub = lane & 15;
#pragma unroll
  for (int mi = 0; mi < 4; ++mi)
#pragma unroll
    for (int j = 0; j < 4; ++j) {
      int rl = wr + mi*16 + rsub + j;
      if (m0 + rl < cnt) {
        size_t orow = (size_t)(off + m0 + rl) * H_ + n0 + wc + csub;
#pragma unroll
        for (int cg = 0; cg < 2; ++cg)
          rowbuf[orow + cg*16] = acc[mi][cg][j];
      }
    }
#undef DN_PF
#undef DN_CVW
#undef DN_CVW1
#undef DN_GLDA
}

// ---------------- phase 4: weighted combine ----------------
__global__ void combine_kernel(const float* __restrict__ ew, const int* __restrict__ row_of,
                               const float* __restrict__ rowbuf, float* __restrict__ out) {
  int idx = blockIdx.x * 256 + threadIdx.x;   // over B_*H_/4
  int t  = idx >> 9;                          // H_/4 = 512
  int h4 = idx & 511;
  float w0 = ew[t*2+0], w1 = ew[t*2+1];
  int r0 = row_of[t*2+0], r1 = row_of[t*2+1];
  float4 a = *(const float4*)(rowbuf + (size_t)r0*H_ + h4*4);
  float4 b = *(const float4*)(rowbuf + (size_t)r1*H_ + h4*4);
  float4 o;
  o.x = w0*a.x + w1*b.x; o.y = w0*a.y + w1*b.y;
  o.z = w0*a.z + w1*b.z; o.w = w0*a.w + w1*b.w;
  *(float4*)(out + (size_t)idx*4) = o;
}

extern "C" void kernel_launch(void* const* d_in, const int* in_sizes, int n_in,
                              void* d_out, int out_size, void* d_ws, size_t ws_size,
                              hipStream_t stream) {
  const float* x   = (const float*)d_in[0];
  const int*   ids = (const int*)d_in[1];
  const float* ew  = (const float*)d_in[2];
  const float* gw  = (const float*)d_in[3];
  const float* uw  = (const float*)d_in[4];
  const float* dwn = (const float*)d_in[5];
  float* out = (float*)d_out;

  char* ws = (char*)d_ws;
  int* counts  = (int*)ws;          // 8
  int* offsets = counts + 8;        // 8
  int* tlist   = offsets + 8;       // NROWS
  int* row_of  = tlist + NROWS;     // NROWS
  int* tile_e  = row_of + NROWS;    // MAXT
  int* tile_m  = tile_e + MAXT;     // MAXT
  __bf16* xb   = (__bf16*)(ws + 32768);
  __bf16* act  = (__bf16*)(ws + 32768 + (size_t)B_*H_*2);
  float* rowbuf = (float*)(ws + 32768 + (size_t)B_*H_*2 + (size_t)NROWS*I_*2);

  hipFuncSetAttribute(reinterpret_cast<const void*>(&gateup_kernel),
                      hipFuncAttributeMaxDynamicSharedMemorySize, 49152);
  hipFuncSetAttribute(reinterpret_cast<const void*>(&down_kernel),
                      hipFuncAttributeMaxDynamicSharedMemorySize, 49152);

  cvtx_kernel<<<B_*H_/(256*8), 256, 0, stream>>>(x, xb);
  route_kernel<<<1, 256, 0, stream>>>(ids, counts, offsets, tlist, row_of, tile_e, tile_m);

  gateup_kernel<<<MAXT*NYG2, 256, 49152, stream>>>(xb, gw, uw, counts, offsets, tlist,
                                                   tile_e, tile_m, act);

  down_kernel<<<MAXT*NYD, 256, 49152, stream>>>(act, dwn, counts, offsets,
                                                tile_e, tile_m, rowbuf);

  combine_kernel<<<(B_*H_/4)/256, 256, 0, stream>>>(ew, row_of, rowbuf, out);
}

// Round 15
// 433.450 us; speedup vs baseline: 1.0105x; 1.0105x over previous
//
#include <hip/hip_runtime.h>
#include <hip/hip_bf16.h>

#define E_ 8
#define H_ 2048
#define I_ 5632
#define B_ 1024
#define K_ 2
#define NROWS (B_*K_)

#define BM 128
#define MAXT 24           // sum_e ceil(cnt_e/128) <= 16 + 8

// gateup: BN=128, BK=32, 32x32x16 MFMA, 64x64 wave tiles
#define GBN 128
#define GBK 32
#define NK2 (H_/GBK)      // 64
#define NYG2 (I_/GBN)     // 44

// down: BN=64, BK=64 (R8-proven)
#define BN 64
#define BK 64
#define NKD (I_/BK)       // 88
#define NYD (H_/BN)       // 32

typedef __attribute__((ext_vector_type(8))) __bf16 bf16x8;
typedef __attribute__((ext_vector_type(4))) float f32x4;
typedef __attribute__((ext_vector_type(16))) float f32x16;

union BF4 { __bf16 b[4]; uint2 q; };
union BF8 { __bf16 b[8]; uint4 q; };

__device__ __forceinline__ void gld_lds16(const void* g, void* l) {
  __builtin_amdgcn_global_load_lds(
      (const __attribute__((address_space(1))) void*)g,
      (__attribute__((address_space(3))) void*)l, 16, 0, 0);
}

#define GLOAD4(dst, ptr) asm volatile("global_load_dwordx4 %0, %1, off" : "=v"(dst) : "v"(ptr))
#define WAITV(N) do { asm volatile("s_waitcnt vmcnt(" #N ")" ::: "memory"); __builtin_amdgcn_sched_barrier(0); } while(0)
#define WAITL()  do { asm volatile("s_waitcnt lgkmcnt(0)" ::: "memory"); __builtin_amdgcn_sched_barrier(0); } while(0)
#define BAR()    __builtin_amdgcn_s_barrier()

#define MSK(c) (((c)&7) ^ (((c)>>2)&7))   // down-kernel swizzle (R8-verified)

// ---------------- phase 0: x (f32) -> xb (bf16) ----------------
__global__ void cvtx_kernel(const float* __restrict__ x, __bf16* __restrict__ xb) {
  int i = (blockIdx.x * 256 + threadIdx.x) * 8;
  float4 a = *(const float4*)(x + i);
  float4 b = *(const float4*)(x + i + 4);
  BF8 r;
  r.b[0] = (__bf16)a.x; r.b[1] = (__bf16)a.y; r.b[2] = (__bf16)a.z; r.b[3] = (__bf16)a.w;
  r.b[4] = (__bf16)b.x; r.b[5] = (__bf16)b.y; r.b[6] = (__bf16)b.z; r.b[7] = (__bf16)b.w;
  *(uint4*)(xb + i) = r.q;
}

// ---------------- phase 1: routing + dense tile list ----------------
__global__ void route_kernel(const int* __restrict__ ids,
                             int* __restrict__ counts, int* __restrict__ offsets,
                             int* __restrict__ tlist, int* __restrict__ row_of,
                             int* __restrict__ tile_e, int* __restrict__ tile_m) {
  __shared__ int sc[E_], sp[E_], so[E_];
  int t = threadIdx.x;
  if (t < E_) { sc[t] = 0; sp[t] = 0; }
  __syncthreads();
  for (int idx = t; idx < NROWS; idx += 256) atomicAdd(&sc[ids[idx]], 1);
  __syncthreads();
  if (t == 0) {
    int acc = 0;
    for (int e = 0; e < E_; ++e) { so[e] = acc; acc += sc[e]; }
    int nt = 0;
    for (int e = 0; e < E_; ++e)
      for (int m0 = 0; m0 < sc[e]; m0 += BM) { tile_e[nt] = e; tile_m[nt] = m0; ++nt; }
    for (; nt < MAXT; ++nt) { tile_e[nt] = 0; tile_m[nt] = 0x7FFFFFFF; }
  }
  __syncthreads();
  for (int idx = t; idx < NROWS; idx += 256) {
    int e = ids[idx];
    int slot = atomicAdd(&sp[e], 1);
    int row = so[e] + slot;
    tlist[row] = idx / K_;
    row_of[idx] = row;
  }
  if (t < E_) { counts[t] = sc[t]; offsets[t] = so[t]; }
}

// ---------------- phase 2: gate+up dual GEMM + SiLU (bf16 act) ----------------
// 128x128 tile, BK=32, mfma_32x32x16, 64x64 wave tiles (2x FLOP per LDS byte).
// LDS 48 KB all-dbuf: A 2x8K [r][slot=g^((r>>1)&3)], B 2x2x8K
// [c][slot=g^((c>>1)&3)^((c>>5)&3)]. PF regs consumed by CVW BEFORE reissue
// (R12/R14 WAR-race fix). Steady outstanding 10 (PF:8 + glda:2), never drained.
__global__ __launch_bounds__(256, 2) void gateup_kernel(
    const __bf16* __restrict__ xb, const float* __restrict__ gw,
    const float* __restrict__ uw, const int* __restrict__ counts,
    const int* __restrict__ offsets, const int* __restrict__ tlist,
    const int* __restrict__ tile_e, const int* __restrict__ tile_m,
    __bf16* __restrict__ act)
{
  extern __shared__ char smem[];
  char* As0 = smem;                 // 8192: 128 rows x 64B (4 granules)
  char* As1 = smem + 8192;
  char* Bg0 = smem + 16384;         // 8192 each: 128 cols x 64B
  char* Bu0 = smem + 24576;
  char* Bg1 = smem + 32768;
  char* Bu1 = smem + 40960;

  const int id = blockIdx.x;                  // [0, 1056)
  const int w  = (id & 7) * 132 + (id >> 3);  // XCD chunking (1056 = 8*132)
  const int tt = w % MAXT;                    // panel sharers adjacent
  const int ny = w / MAXT;                    // [0, 44)
  const int e  = tile_e[tt];
  const int m0 = tile_m[tt];
  const int cnt = counts[e];
  if (m0 >= cnt) return;
  const int off = offsets[e];
  const int n0 = ny * GBN;

  const int tid  = threadIdx.x;
  const int lane = tid & 63;
  const int wave = tid >> 6;         // 0..3
  const int wr = (wave >> 1) * 64;   // rows 0,64
  const int wc = (wave & 1) * 64;    // cols 0,64

  // ---- A glda sources: 2 granules/thread; LDS linear; source pre-unswizzled
  const __bf16* asrc0; const __bf16* asrc1;
  int ad0, ad1;
  {
    const __bf16* s[2]; int d[2];
#pragma unroll
    for (int j = 0; j < 2; ++j) {
      int f = j*256 + tid;           // granule 0..511
      int r = f >> 2;                // 0..127
      int sl = f & 3;
      int cs = sl ^ ((r >> 1) & 3);  // source granule
      int rr = m0 + r; if (rr >= cnt) rr = cnt - 1;
      int tok = tlist[off + rr];
      s[j] = xb + (size_t)tok * H_ + cs*8;
      d[j] = f * 16;
    }
    asrc0=s[0]; asrc1=s[1]; ad0=d[0]; ad1=d[1];
  }

  // ---- B staging: thread owns cols 4q..4q+3, k-rows kb..kb+3 (dwordx4)
  const int q  = tid & 31;
  const int kb = (tid >> 5) * 4;     // 0..28
  const float* pg0 = gw + ((size_t)e*H_ + kb + 0)*I_ + n0 + 4*q;
  const float* pg1 = gw + ((size_t)e*H_ + kb + 1)*I_ + n0 + 4*q;
  const float* pg2 = gw + ((size_t)e*H_ + kb + 2)*I_ + n0 + 4*q;
  const float* pg3 = gw + ((size_t)e*H_ + kb + 3)*I_ + n0 + 4*q;
  const float* pu0 = uw + ((size_t)e*H_ + kb + 0)*I_ + n0 + 4*q;
  const float* pu1 = uw + ((size_t)e*H_ + kb + 1)*I_ + n0 + 4*q;
  const float* pu2 = uw + ((size_t)e*H_ + kb + 2)*I_ + n0 + 4*q;
  const float* pu3 = uw + ((size_t)e*H_ + kb + 3)*I_ + n0 + 4*q;
  int bw0, bw1, bw2, bw3;
  {
    int g    = kb >> 3;              // granule 0..3
    int half = (kb & 4) << 1;        // 0 or 8 bytes
    int b[4];
#pragma unroll
    for (int i = 0; i < 4; ++i) {
      int c = 4*q + i;
      int slot = g ^ ((c >> 1) & 3) ^ ((c >> 5) & 3);
      b[i] = c*64 + slot*16 + half;
    }
    bw0=b[0]; bw1=b[1]; bw2=b[2]; bw3=b[3];
  }

  // ---- COMPUTE read offsets (base slot xor'd with granule at use)
  int aof0, aof1;          // A: mi=0,1
  int bof0, bof1;          // B: ni=0,1
  const int ls2 = lane >> 5;          // 0,1
  {
    int r0 = wr + (lane & 31);
    int r1 = r0 + 32;
    aof0 = r0*64 + (((r0 >> 1) & 3) << 4);
    aof1 = r1*64 + (((r1 >> 1) & 3) << 4);
    int c0 = wc + (lane & 31);
    int c1 = c0 + 32;
    bof0 = c0*64 + ((((c0 >> 1) & 3) ^ ((c0 >> 5) & 3)) << 4);
    bof1 = c1*64 + ((((c1 >> 1) & 3) ^ ((c1 >> 5) & 3)) << 4);
  }

  f32x4 vg_0,vg_1,vg_2,vg_3, vu_0,vu_1,vu_2,vu_3;   // single PF set

  f32x16 accg00, accg01, accg10, accg11;
  f32x16 accu00, accu01, accu10, accu11;
#pragma unroll
  for (int i = 0; i < 16; ++i) {
    accg00[i]=0.f; accg01[i]=0.f; accg10[i]=0.f; accg11[i]=0.f;
    accu00[i]=0.f; accu01[i]=0.f; accu10[i]=0.f; accu11[i]=0.f;
  }

  auto COMPUTE = [&](const char* Ap, const char* Bgp, const char* Bup) {
    __builtin_amdgcn_s_setprio(1);
#pragma unroll
    for (int kstep = 0; kstep < 2; ++kstep) {
      const int gx = (kstep*2 + ls2) << 4;    // granule byte-xor
      bf16x8 a0 = *(const bf16x8*)(Ap + (aof0 ^ gx));
      bf16x8 a1 = *(const bf16x8*)(Ap + (aof1 ^ gx));
      bf16x8 g0 = *(const bf16x8*)(Bgp + (bof0 ^ gx));
      bf16x8 g1 = *(const bf16x8*)(Bgp + (bof1 ^ gx));
      bf16x8 u0 = *(const bf16x8*)(Bup + (bof0 ^ gx));
      bf16x8 u1 = *(const bf16x8*)(Bup + (bof1 ^ gx));
      accg00 = __builtin_amdgcn_mfma_f32_32x32x16_bf16(a0, g0, accg00, 0,0,0);
      accg10 = __builtin_amdgcn_mfma_f32_32x32x16_bf16(a1, g0, accg10, 0,0,0);
      accg01 = __builtin_amdgcn_mfma_f32_32x32x16_bf16(a0, g1, accg01, 0,0,0);
      accg11 = __builtin_amdgcn_mfma_f32_32x32x16_bf16(a1, g1, accg11, 0,0,0);
      accu00 = __builtin_amdgcn_mfma_f32_32x32x16_bf16(a0, u0, accu00, 0,0,0);
      accu10 = __builtin_amdgcn_mfma_f32_32x32x16_bf16(a1, u0, accu10, 0,0,0);
      accu01 = __builtin_amdgcn_mfma_f32_32x32x16_bf16(a0, u1, accu01, 0,0,0);
      accu11 = __builtin_amdgcn_mfma_f32_32x32x16_bf16(a1, u1, accu11, 0,0,0);
    }
    __builtin_amdgcn_s_setprio(0);
  };

#define GU_PF(KPF) do { size_t o_ = (size_t)(KPF)*(size_t)GBK*(size_t)I_; \
    GLOAD4(vg_0, pg0+o_); GLOAD4(vu_0, pu0+o_); \
    GLOAD4(vg_1, pg1+o_); GLOAD4(vu_1, pu1+o_); \
    GLOAD4(vg_2, pg2+o_); GLOAD4(vu_2, pu2+o_); \
    GLOAD4(vg_3, pg3+o_); GLOAD4(vu_3, pu3+o_); } while(0)

#define GU_CVW1(BB, V0, V1, V2, V3, BWI, I) do { BF4 p_; \
    p_.b[0]=(__bf16)V0[I]; p_.b[1]=(__bf16)V1[I]; p_.b[2]=(__bf16)V2[I]; p_.b[3]=(__bf16)V3[I]; \
    *(uint2*)((BB)+BWI) = p_.q; } while(0)

#define GU_CVW(BG, BU) do { \
    GU_CVW1(BG, vg_0, vg_1, vg_2, vg_3, bw0, 0); \
    GU_CVW1(BG, vg_0, vg_1, vg_2, vg_3, bw1, 1); \
    GU_CVW1(BG, vg_0, vg_1, vg_2, vg_3, bw2, 2); \
    GU_CVW1(BG, vg_0, vg_1, vg_2, vg_3, bw3, 3); \
    GU_CVW1(BU, vu_0, vu_1, vu_2, vu_3, bw0, 0); \
    GU_CVW1(BU, vu_0, vu_1, vu_2, vu_3, bw1, 1); \
    GU_CVW1(BU, vu_0, vu_1, vu_2, vu_3, bw2, 2); \
    GU_CVW1(BU, vu_0, vu_1, vu_2, vu_3, bw3, 3); } while(0)

#define GU_GLDA(DST, KPF) do { size_t k_ = (size_t)(KPF)*(size_t)GBK; \
    gld_lds16(asrc0 + k_, (DST)+ad0); gld_lds16(asrc1 + k_, (DST)+ad1); } while(0)

  // ---- prologue: loop-top invariant = PF(kt+1):8 + glda(kt+1):2 = 10
  GU_PF(0);             // 8
  GU_GLDA(As0, 0);      // -> 10
  WAITV(2);             // retire PF(0); regs ready; glda(0):2 left
  GU_CVW(Bg0, Bu0);     // B(0) (regs consumed)
  GU_PF(1);             // -> 10
  GU_GLDA(As1, 1);      // -> 12
  WAITV(10);            // retire glda(0): As0 landed (own)
  WAITL();
  BAR();                // As0 + B(0) visible

#pragma unroll 1
  for (int kt = 0; kt < NK2; kt += 2) {
    { // even: compute As0/B0; CVW kt+1 -> buf1; PF kt+2; glda As0 <- kt+2
      int kpf = kt + 2; if (kpf > NK2-1) kpf = NK2-1;
      COMPUTE(As0, Bg0, Bu0);
      WAITV(2);                    // retire PF(kt+1); keep glda(kt+1)
      GU_CVW(Bg1, Bu1);            // consume regs
      GU_PF(kpf);                  // reissue AFTER consumption -> 10
      WAITV(8);                    // retire glda(kt+1): As1 landed (own)
      WAITL();
      BAR();                       // As1 + B(kt+1) visible; As0/B0 free
      GU_GLDA(As0, kpf);           // -> 10
    }
    { // odd: mirror
      int kpf = kt + 3; if (kpf > NK2-1) kpf = NK2-1;
      COMPUTE(As1, Bg1, Bu1);
      WAITV(2);
      GU_CVW(Bg0, Bu0);
      GU_PF(kpf);
      WAITV(8);
      WAITL();
      BAR();
      GU_GLDA(As1, kpf);
    }
  }
  WAITV(0);
  WAITL();

  // ---- epilogue: SiLU(g)*u -> bf16 act (32x32 C/D layout: col=lane&31,
  // row=(reg&3)+8*(reg>>2)+4*(lane>>5); m74/m101)
  const int cl = lane & 31;
  const int rbase = 4 * (lane >> 5);
#define GU_EPI(ACCG, ACCU, MI, NI) do { \
    _Pragma("unroll") \
    for (int reg = 0; reg < 16; ++reg) { \
      int rl = wr + (MI)*32 + (reg & 3) + 8*(reg >> 2) + rbase; \
      if (m0 + rl < cnt) { \
        size_t o = (size_t)(off + m0 + rl) * I_ + n0 + wc + (NI)*32 + cl; \
        float g_ = ACCG[reg]; \
        float u_ = ACCU[reg]; \
        float sg_ = g_ / (1.0f + __expf(-g_)); \
        act[o] = (__bf16)(sg_ * u_); \
      } \
    } } while(0)
  GU_EPI(accg00, accu00, 0, 0);
  GU_EPI(accg01, accu01, 0, 1);
  GU_EPI(accg10, accu10, 1, 0);
  GU_EPI(accg11, accu11, 1, 1);
#undef GU_EPI
#undef GU_PF
#undef GU_CVW
#undef GU_CVW1
#undef GU_GLDA
}

// ---------------- phase 3: down GEMM -> rowbuf (f32) ----------------
// R8-proven: 48 KB LDS -> 3 blocks/CU. Steady outstanding 8 (PF:4 + GLDA:4).
__global__ __launch_bounds__(256, 3) void down_kernel(
    const __bf16* __restrict__ act, const float* __restrict__ dw,
    const int* __restrict__ counts, const int* __restrict__ offsets,
    const int* __restrict__ tile_e, const int* __restrict__ tile_m,
    float* __restrict__ rowbuf)
{
  extern __shared__ char smem[];
  char* As0 = smem;
  char* As1 = smem + 16384;
  char* Bs0 = smem + 32768;
  char* Bs1 = smem + 40960;

  const int id = blockIdx.x;                  // [0, 768)
  const int w  = (id & 7) * 96 + (id >> 3);   // 768 = 8*96
  const int tt = w % MAXT;
  const int ny = w / MAXT;                    // [0, 32)
  const int e  = tile_e[tt];
  const int m0 = tile_m[tt];
  const int cnt = counts[e];
  if (m0 >= cnt) return;
  const int off = offsets[e];
  const int n0 = ny * BN;

  const int tid  = threadIdx.x;
  const int lane = tid & 63;
  const int wave = tid >> 6;
  const int wr = (wave >> 1) * 64;
  const int wc = (wave & 1) * 32;

  const __bf16* asrc0; const __bf16* asrc1; const __bf16* asrc2; const __bf16* asrc3;
  int ad0, ad1, ad2, ad3;
  {
    const __bf16* s[4]; int d[4];
#pragma unroll
    for (int i = 0; i < 4; ++i) {
      int f = i*256 + tid;
      int r = f >> 3, cs = f & 7;
      int rr = m0 + r; if (rr >= cnt) rr = cnt - 1;
      s[i] = act + (size_t)(off + rr) * I_ + ((cs ^ (r & 7)) << 3);
      d[i] = f * 16;
    }
    asrc0=s[0]; asrc1=s[1]; asrc2=s[2]; asrc3=s[3];
    ad0=d[0]; ad1=d[1]; ad2=d[2]; ad3=d[3];
  }

  const int cq = tid & 15;
  const int kb = (tid >> 4) * 4;
  const float* pd0 = dw + ((size_t)e*I_ + kb + 0)*H_ + n0 + 4*cq;
  const float* pd1 = dw + ((size_t)e*I_ + kb + 1)*H_ + n0 + 4*cq;
  const float* pd2 = dw + ((size_t)e*I_ + kb + 2)*H_ + n0 + 4*cq;
  const float* pd3 = dw + ((size_t)e*I_ + kb + 3)*H_ + n0 + 4*cq;
  const int slot = kb >> 3;
  const int half = (kb & 4) << 1;
  int bw0, bw1, bw2, bw3;
  {
    int b[4];
#pragma unroll
    for (int i = 0; i < 4; ++i) {
      int c = 4*cq + i;
      b[i] = c*128 + ((slot ^ MSK(c)) << 4) + half;
    }
    bw0=b[0]; bw1=b[1]; bw2=b[2]; bw3=b[3];
  }

  f32x4 vdA_0,vdA_1,vdA_2,vdA_3;
  f32x4 vdB_0,vdB_1,vdB_2,vdB_3;

  f32x4 acc[4][2];
#pragma unroll
  for (int i = 0; i < 4; ++i)
#pragma unroll
    for (int j = 0; j < 2; ++j) acc[i][j] = (f32x4){0.f,0.f,0.f,0.f};

  auto COMPUTE = [&](const char* Ab, const char* Bb) {
    __builtin_amdgcn_s_setprio(1);
#pragma unroll
    for (int kk = 0; kk < 2; ++kk) {
      const int ks = kk*4 + (lane >> 4);
      const int r0 = wr + (lane & 15);
      const int swa = (ks ^ (r0 & 7)) << 4;
      bf16x8 a0 = *(const bf16x8*)(Ab + (r0 +  0)*128 + swa);
      bf16x8 a1 = *(const bf16x8*)(Ab + (r0 + 16)*128 + swa);
      bf16x8 a2 = *(const bf16x8*)(Ab + (r0 + 32)*128 + swa);
      bf16x8 a3 = *(const bf16x8*)(Ab + (r0 + 48)*128 + swa);
      const int c0 = wc + (lane & 15);
      const int swb0 = (ks ^ MSK(c0)) << 4;
      const int swb1 = swb0 ^ (4 << 4);
      bf16x8 b0 = *(const bf16x8*)(Bb + c0*128 + swb0);
      bf16x8 b1 = *(const bf16x8*)(Bb + (c0+16)*128 + swb1);
      acc[0][0] = __builtin_amdgcn_mfma_f32_16x16x32_bf16(a0, b0, acc[0][0], 0,0,0);
      acc[1][0] = __builtin_amdgcn_mfma_f32_16x16x32_bf16(a1, b0, acc[1][0], 0,0,0);
      acc[2][0] = __builtin_amdgcn_mfma_f32_16x16x32_bf16(a2, b0, acc[2][0], 0,0,0);
      acc[3][0] = __builtin_amdgcn_mfma_f32_16x16x32_bf16(a3, b0, acc[3][0], 0,0,0);
      acc[0][1] = __builtin_amdgcn_mfma_f32_16x16x32_bf16(a0, b1, acc[0][1], 0,0,0);
      acc[1][1] = __builtin_amdgcn_mfma_f32_16x16x32_bf16(a1, b1, acc[1][1], 0,0,0);
      acc[2][1] = __builtin_amdgcn_mfma_f32_16x16x32_bf16(a2, b1, acc[2][1], 0,0,0);
      acc[3][1] = __builtin_amdgcn_mfma_f32_16x16x32_bf16(a3, b1, acc[3][1], 0,0,0);
    }
    __builtin_amdgcn_s_setprio(0);
  };

#define DN_PF(S, KPF) do { size_t o_ = (size_t)(KPF)*(size_t)BK*(size_t)H_; \
    GLOAD4(vd##S##_0, pd0+o_); GLOAD4(vd##S##_1, pd1+o_); \
    GLOAD4(vd##S##_2, pd2+o_); GLOAD4(vd##S##_3, pd3+o_); } while(0)

#define DN_CVW1(BB, V0, V1, V2, V3, BWI, I) do { BF4 p_; \
    p_.b[0]=(__bf16)V0[I]; p_.b[1]=(__bf16)V1[I]; p_.b[2]=(__bf16)V2[I]; p_.b[3]=(__bf16)V3[I]; \
    *(uint2*)((BB)+BWI) = p_.q; } while(0)

#define DN_CVW(S, BB) do { \
    DN_CVW1(BB, vd##S##_0, vd##S##_1, vd##S##_2, vd##S##_3, bw0, 0); \
    DN_CVW1(BB, vd##S##_0, vd##S##_1, vd##S##_2, vd##S##_3, bw1, 1); \
    DN_CVW1(BB, vd##S##_0, vd##S##_1, vd##S##_2, vd##S##_3, bw2, 2); \
    DN_CVW1(BB, vd##S##_0, vd##S##_1, vd##S##_2, vd##S##_3, bw3, 3); } while(0)

#define DN_GLDA(DST, KPF) do { size_t k_ = (size_t)(KPF)*(size_t)BK; \
    gld_lds16(asrc0 + k_, (DST)+ad0); gld_lds16(asrc1 + k_, (DST)+ad1); \
    gld_lds16(asrc2 + k_, (DST)+ad2); gld_lds16(asrc3 + k_, (DST)+ad3); } while(0)

  DN_PF(A, 0);          // 4
  DN_GLDA(As0, 0);      // -> 8
  WAITV(4);             // drain PF(0)
  DN_CVW(A, Bs0);
  DN_PF(B, 1);          // -> 8
  DN_GLDA(As1, 1);      // -> 12
  WAITV(8);             // drain GLDA(0); PF(1)+GLDA(1)=8 left
  WAITL();
  BAR();

#pragma unroll 1
  for (int kt = 0; kt < NKD; kt += 2) {
    {
      int kpf = kt + 2; if (kpf > NKD-1) kpf = NKD-1;
      DN_PF(A, kpf);               // -> 12
      COMPUTE(As0, Bs0);
      WAITV(8);                    // drain PF_B(kt+1)
      DN_CVW(B, Bs1);
      WAITV(4);                    // drain GLDA(kt+1)
      WAITL();
      BAR();
      DN_GLDA(As0, kpf);           // -> 8
    }
    {
      int kpf = kt + 3; if (kpf > NKD-1) kpf = NKD-1;
      DN_PF(B, kpf);
      COMPUTE(As1, Bs1);
      WAITV(8);
      DN_CVW(A, Bs0);
      WAITV(4);
      WAITL();
      BAR();
      DN_GLDA(As1, kpf);
    }
  }
  WAITV(0);
  WAITL();

  const int rsub = (lane >> 4) * 4;
  const int csub = lane & 15;
#pragma unroll
  for (int mi = 0; mi < 4; ++mi)
#pragma unroll
    for (int j = 0; j < 4; ++j) {
      int rl = wr + mi*16 + rsub + j;
      if (m0 + rl < cnt) {
        size_t orow = (size_t)(off + m0 + rl) * H_ + n0 + wc + csub;
#pragma unroll
        for (int cg = 0; cg < 2; ++cg)
          rowbuf[orow + cg*16] = acc[mi][cg][j];
      }
    }
#undef DN_PF
#undef DN_CVW
#undef DN_CVW1
#undef DN_GLDA
}

// ---------------- phase 4: weighted combine ----------------
__global__ void combine_kernel(const float* __restrict__ ew, const int* __restrict__ row_of,
                               const float* __restrict__ rowbuf, float* __restrict__ out) {
  int idx = blockIdx.x * 256 + threadIdx.x;   // over B_*H_/4
  int t  = idx >> 9;                          // H_/4 = 512
  int h4 = idx & 511;
  float w0 = ew[t*2+0], w1 = ew[t*2+1];
  int r0 = row_of[t*2+0], r1 = row_of[t*2+1];
  float4 a = *(const float4*)(rowbuf + (size_t)r0*H_ + h4*4);
  float4 b = *(const float4*)(rowbuf + (size_t)r1*H_ + h4*4);
  float4 o;
  o.x = w0*a.x + w1*b.x; o.y = w0*a.y + w1*b.y;
  o.z = w0*a.z + w1*b.z; o.w = w0*a.w + w1*b.w;
  *(float4*)(out + (size_t)idx*4) = o;
}

extern "C" void kernel_launch(void* const* d_in, const int* in_sizes, int n_in,
                              void* d_out, int out_size, void* d_ws, size_t ws_size,
                              hipStream_t stream) {
  const float* x   = (const float*)d_in[0];
  const int*   ids = (const int*)d_in[1];
  const float* ew  = (const float*)d_in[2];
  const float* gw  = (const float*)d_in[3];
  const float* uw  = (const float*)d_in[4];
  const float* dwn = (const float*)d_in[5];
  float* out = (float*)d_out;

  char* ws = (char*)d_ws;
  int* counts  = (int*)ws;          // 8
  int* offsets = counts + 8;        // 8
  int* tlist   = offsets + 8;       // NROWS
  int* row_of  = tlist + NROWS;     // NROWS
  int* tile_e  = row_of + NROWS;    // MAXT
  int* tile_m  = tile_e + MAXT;     // MAXT
  __bf16* xb   = (__bf16*)(ws + 32768);
  __bf16* act  = (__bf16*)(ws + 32768 + (size_t)B_*H_*2);
  float* rowbuf = (float*)(ws + 32768 + (size_t)B_*H_*2 + (size_t)NROWS*I_*2);

  hipFuncSetAttribute(reinterpret_cast<const void*>(&gateup_kernel),
                      hipFuncAttributeMaxDynamicSharedMemorySize, 49152);
  hipFuncSetAttribute(reinterpret_cast<const void*>(&down_kernel),
                      hipFuncAttributeMaxDynamicSharedMemorySize, 49152);

  cvtx_kernel<<<B_*H_/(256*8), 256, 0, stream>>>(x, xb);
  route_kernel<<<1, 256, 0, stream>>>(ids, counts, offsets, tlist, row_of, tile_e, tile_m);

  gateup_kernel<<<MAXT*NYG2, 256, 49152, stream>>>(xb, gw, uw, counts, offsets, tlist,
                                                   tile_e, tile_m, act);

  down_kernel<<<MAXT*NYD, 256, 49152, stream>>>(act, dwn, counts, offsets,
                                                tile_e, tile_m, rowbuf);

  combine_kernel<<<(B_*H_/4)/256, 256, 0, stream>>>(ew, row_of, rowbuf, out);
}